// Round 5
// baseline (438.357 us; speedup 1.0000x reference)
//
#include <hip/hip_runtime.h>
#include <cstdint>
#include <cstddef>

typedef __attribute__((ext_vector_type(8))) short short8;
typedef __attribute__((ext_vector_type(8))) unsigned short ushort8;
typedef __attribute__((ext_vector_type(4))) float f32x4;

#define DEV static __device__ __forceinline__

DEV unsigned short f2bf(float x) {
  union { float f; unsigned u; } v; v.f = x;
  unsigned r = v.u + 0x7fffu + ((v.u >> 16) & 1u);
  return (unsigned short)(r >> 16);
}
DEV float bf2f(unsigned short u) {
  union { unsigned u; float f; } v; v.u = ((unsigned)u) << 16;
  return v.f;
}
// pack two fp32 -> bf16x2 dword, round-half-up; v_perm merges the two hi16s
DEV unsigned pack2bf(float lo, float hi) {
  union { float f; unsigned u; } a, b; a.f = lo; b.f = hi;
  return __builtin_amdgcn_perm(b.u + 0x8000u, a.u + 0x8000u, 0x07060302u);
}
DEV f32x4 mfma16(short8 a, short8 b, f32x4 c) {
  return __builtin_amdgcn_mfma_f32_16x16x32_bf16(a, b, c, 0, 0, 0);
}

// async global->LDS, 16B per lane
typedef __attribute__((address_space(1))) unsigned int g_u32;
typedef __attribute__((address_space(3))) unsigned int l_u32;
DEV void glds16(const unsigned short* g, unsigned short* l) {
  __builtin_amdgcn_global_load_lds((g_u32*)g, (l_u32*)l, 16, 0, 0);
}

constexpr int Bc = 4, Nc = 2048, Dc = 1024, Hc = 16, DKc = 16, DVc = 64, DIc = 1280;
constexpr int Mc = Bc * Nc;  // 8192

// ---------------- elementwise fp32 -> bf16 ----------------
__global__ __launch_bounds__(256) void convert_x(const float* __restrict__ X,
                                                 unsigned short* __restrict__ Xb, int total8) {
  int i = blockIdx.x * 256 + threadIdx.x;
  if (i >= total8) return;
  const float4* p = (const float4*)(X + (size_t)i * 8);
  float4 a = p[0], b = p[1];
  ushort8 o;
  o[0] = f2bf(a.x); o[1] = f2bf(a.y); o[2] = f2bf(a.z); o[3] = f2bf(a.w);
  o[4] = f2bf(b.x); o[5] = f2bf(b.y); o[6] = f2bf(b.z); o[7] = f2bf(b.w);
  *(ushort8*)(Xb + (size_t)i * 8) = o;
}

// ---------------- W[K][N] fp32 -> WT[N][K] bf16 ----------------
__global__ __launch_bounds__(256) void transpose_convert(const float* __restrict__ W,
                                                         unsigned short* __restrict__ WT,
                                                         int K, int N) {
  __shared__ unsigned short t[64][72];
  int k0 = blockIdx.x * 64, n0 = blockIdx.y * 64;
  int tid = threadIdx.x;
#pragma unroll
  for (int it = 0; it < 16; ++it) {
    int f = it * 256 + tid;
    int r = f >> 6, c = f & 63;
    t[c][r] = f2bf(W[(size_t)(k0 + r) * N + n0 + c]);
  }
  __syncthreads();
#pragma unroll
  for (int it = 0; it < 16; ++it) {
    int f = it * 256 + tid;
    int r = f >> 6, c = f & 63;
    WT[(size_t)(n0 + r) * K + k0 + c] = t[r][c];
  }
}

// ---------------- C[M][N] = A[M][K] * BT[N][K]^T, m97-style global_load_lds ----------------
template <int OUT_BF16>
__global__ __launch_bounds__(256) void gemm_glds(const unsigned short* __restrict__ A,
                                                 const unsigned short* __restrict__ BT,
                                                 void* __restrict__ Cout,
                                                 int Mq, int Nq, int Kq) {
  __shared__ unsigned short As[128 * 64];
  __shared__ unsigned short Bs[128 * 64];
  int row0 = blockIdx.x * 128, col0 = blockIdx.y * 128;
  int tid = threadIdx.x, lane = tid & 63, wave = tid >> 6;
  int wm = wave >> 1, wn = wave & 1;
  int ql = lane >> 4, l16 = lane & 15;
  int r8 = lane >> 3, cbl = (lane & 7) ^ r8;

  const unsigned short* gA = A + (size_t)(row0 + wave * 32 + r8) * Kq + cbl * 8;
  const unsigned short* gB = BT + (size_t)(col0 + wave * 32 + r8) * Kq + cbl * 8;

  f32x4 acc[4][4];
#pragma unroll
  for (int i = 0; i < 4; i++)
#pragma unroll
    for (int j = 0; j < 4; j++) acc[i][j] = (f32x4){0.f, 0.f, 0.f, 0.f};

  for (int k0 = 0; k0 < Kq; k0 += 64) {
    __syncthreads();
#pragma unroll
    for (int i = 0; i < 4; ++i) {
      glds16(gA + (size_t)(i * 8) * Kq + k0, &As[(wave * 32 + i * 8) * 64]);
      glds16(gB + (size_t)(i * 8) * Kq + k0, &Bs[(wave * 32 + i * 8) * 64]);
    }
    __syncthreads();
#pragma unroll
    for (int kk = 0; kk < 64; kk += 32) {
      short8 af[4], bfr[4];
#pragma unroll
      for (int t = 0; t < 4; t++) {
        int row = wm * 64 + t * 16 + l16;
        int cb = (kk >> 3) + ql;
        af[t] = *(const short8*)&As[row * 64 + ((cb ^ (row & 7)) << 3)];
      }
#pragma unroll
      for (int t = 0; t < 4; t++) {
        int row = wn * 64 + t * 16 + l16;
        int cb = (kk >> 3) + ql;
        bfr[t] = *(const short8*)&Bs[row * 64 + ((cb ^ (row & 7)) << 3)];
      }
#pragma unroll
      for (int i = 0; i < 4; i++)
#pragma unroll
        for (int j = 0; j < 4; j++) acc[i][j] = mfma16(af[i], bfr[j], acc[i][j]);
    }
  }
#pragma unroll
  for (int i = 0; i < 4; i++)
#pragma unroll
    for (int j = 0; j < 4; j++)
#pragma unroll
      for (int r = 0; r < 4; r++) {
        int rr = row0 + wm * 64 + i * 16 + ql * 4 + r;
        int cc = col0 + wn * 64 + j * 16 + l16;
        if (OUT_BF16)
          ((unsigned short*)Cout)[(size_t)rr * Nq + cc] = f2bf(acc[i][j][r]);
        else
          ((float*)Cout)[(size_t)rr * Nq + cc] = acc[i][j][r];
      }
}

// ---------------- per-head normalize (gates now handled in attn epilogue) ----------------
__global__ __launch_bounds__(256) void norm_kernel(const unsigned short* __restrict__ QG,
                                                   const unsigned short* __restrict__ KV,
                                                   unsigned short* __restrict__ Qn,
                                                   unsigned short* __restrict__ Kn,
                                                   unsigned short* __restrict__ Vtg) {
  int g = blockIdx.x * 256 + threadIdx.x;
  int n = g & (Nc - 1), bh = g >> 11;
  int h = bh & 15, b = bh >> 4;
  size_t src = ((size_t)(b * Nc + n)) * DIc + h * 80;

  {
    ushort8 u0 = *(const ushort8*)&QG[src];
    ushort8 u1 = *(const ushort8*)&QG[src + 8];
    float q[16], ss = 0.f;
#pragma unroll
    for (int i = 0; i < 8; i++) { q[i] = bf2f(u0[i]); q[8 + i] = bf2f(u1[i]); }
#pragma unroll
    for (int i = 0; i < 16; i++) ss += q[i] * q[i];
    float sc = 1.f / fmaxf(sqrtf(ss), 1e-12f);
    ushort8 o0, o1;
#pragma unroll
    for (int i = 0; i < 8; i++) { o0[i] = f2bf(q[i] * sc); o1[i] = f2bf(q[8 + i] * sc); }
    size_t dst = ((size_t)bh * Nc + n) * DKc;
    *(ushort8*)&Qn[dst] = o0;
    *(ushort8*)&Qn[dst + 8] = o1;
  }
  {
    ushort8 u0 = *(const ushort8*)&KV[src];
    ushort8 u1 = *(const ushort8*)&KV[src + 8];
    float q[16], ss = 0.f;
#pragma unroll
    for (int i = 0; i < 8; i++) { q[i] = bf2f(u0[i]); q[8 + i] = bf2f(u1[i]); }
#pragma unroll
    for (int i = 0; i < 16; i++) ss += q[i] * q[i];
    float sc = 1.f / fmaxf(sqrtf(ss), 1e-12f);
    ushort8 o0, o1;
#pragma unroll
    for (int i = 0; i < 8; i++) { o0[i] = f2bf(q[i] * sc); o1[i] = f2bf(q[8 + i] * sc); }
    size_t dst = ((size_t)bh * Nc + n) * DKc;
    *(ushort8*)&Kn[dst] = o0;
    *(ushort8*)&Kn[dst + 8] = o1;
  }
  {
    ushort8 u[8];
#pragma unroll
    for (int i = 0; i < 8; i++) u[i] = *(const ushort8*)&KV[src + 16 + i * 8];
    float ss = 0.f;
#pragma unroll
    for (int i = 0; i < 8; i++)
#pragma unroll
      for (int j = 0; j < 8; j++) { float x = bf2f(u[i][j]); ss += x * x; }
    float sc = 1.f / fmaxf(sqrtf(ss), 1e-12f);
#pragma unroll
    for (int i = 0; i < 8; i++)
#pragma unroll
      for (int j = 0; j < 8; j++) {
        int d = i * 8 + j;
        Vtg[((size_t)bh * DVc + d) * Nc + n] = f2bf(bf2f(u[i][j]) * sc);
      }
  }
}

// ---------------- barrier-free relu^2 attention ----------------
// 1024 blocks (XCD-swizzled), 4 independent waves/block; each wave owns 32 q's
// and iterates all 2048 keys. NO LDS / NO barriers in the k-loop: the relu^2'd
// S^T C-regs feed PV's B-operand directly; V^T A-frags are loaded with the
// matching permuted key order (mfma-k ql*8+j <-> global key kb+(j>=4)*16+4ql+(j&3),
// identical bijection on both operands). Epilogue: shfl-xor row-norm, gate from
// QG, 17.4KB LDS transpose for coalesced stores (single barrier).
__global__ __launch_bounds__(256) void attn_kernel(const unsigned short* __restrict__ Qn,
                                                   const unsigned short* __restrict__ Kn,
                                                   const unsigned short* __restrict__ Vtg,
                                                   const unsigned short* __restrict__ QG,
                                                   unsigned short* __restrict__ outpre) {
  __shared__ unsigned short of[128][68];

  int gid = blockIdx.x;
  int xcd = gid & 7, slot = gid >> 3;
  int bh = xcd * 8 + (slot & 7);
  int q0 = (slot >> 3) * 128;
  int b = bh >> 4, h = bh & 15;
  int tid = threadIdx.x, lane = tid & 63, wave = tid >> 6;
  int ql = lane >> 4, l16 = lane & 15;
  int qw0 = q0 + wave * 32;  // this wave's 32-query base

  const short8 zz = {0, 0, 0, 0, 0, 0, 0, 0};

  // Q fragments (B-operand of S-mfma), resident: q = qw0 + qt*16 + l16
  short8 qf[2];
#pragma unroll
  for (int qt = 0; qt < 2; ++qt)
    qf[qt] = (ql < 2)
                 ? *(const short8*)&Qn[((size_t)bh * Nc + qw0 + qt * 16 + l16) * DKc + ql * 8]
                 : zz;

  const unsigned short* vrow = Vtg + ((size_t)bh * DVc + l16) * Nc;  // + dt*16*Nc
  const unsigned short* krow = Kn + ((size_t)bh * Nc) * DKc;

  f32x4 acc[4][2];
#pragma unroll
  for (int dt = 0; dt < 4; dt++) { acc[dt][0] = (f32x4){0.f,0.f,0.f,0.f}; acc[dt][1] = (f32x4){0.f,0.f,0.f,0.f}; }

  for (int kt = 0; kt < Nc / 128; ++kt) {
    int k0 = kt * 128;
    // K fragments for this tile (A-operand of S-mfma)
    short8 kf[8];
#pragma unroll
    for (int kh = 0; kh < 8; ++kh)
      kf[kh] = (ql < 2)
                   ? *(const short8*)&krow[(size_t)(k0 + kh * 16 + l16) * DKc + ql * 8]
                   : zz;
#pragma unroll
    for (int p = 0; p < 4; ++p) {  // 32-key group [k0+p*32, +32)
      // S^T: C lane(ql,l16) = S^T[key = kb + {0,16} + ql*4 + r][q = qt*16+l16]
      f32x4 c0[2], c1[2];
#pragma unroll
      for (int qt = 0; qt < 2; ++qt) {
        c0[qt] = mfma16(kf[2 * p], qf[qt], (f32x4){0.f, 0.f, 0.f, 0.f});
        c1[qt] = mfma16(kf[2 * p + 1], qf[qt], (f32x4){0.f, 0.f, 0.f, 0.f});
      }
      // relu^2 + pack -> PV B-frag (k-slots in permuted key order)
      short8 pf[2];
#pragma unroll
      for (int qt = 0; qt < 2; ++qt) {
        float a0 = fmaxf(c0[qt][0], 0.f) ; a0 *= a0;
        float a1 = fmaxf(c0[qt][1], 0.f) ; a1 *= a1;
        float a2 = fmaxf(c0[qt][2], 0.f) ; a2 *= a2;
        float a3 = fmaxf(c0[qt][3], 0.f) ; a3 *= a3;
        float b0 = fmaxf(c1[qt][0], 0.f) ; b0 *= b0;
        float b1 = fmaxf(c1[qt][1], 0.f) ; b1 *= b1;
        float b2 = fmaxf(c1[qt][2], 0.f) ; b2 *= b2;
        float b3 = fmaxf(c1[qt][3], 0.f) ; b3 *= b3;
        union { short8 s; uint4 u; } w;
        w.u.x = pack2bf(a0, a1);
        w.u.y = pack2bf(a2, a3);
        w.u.z = pack2bf(b0, b1);
        w.u.w = pack2bf(b2, b3);
        pf[qt] = w.s;
      }
      // PV: A = V^T frags in the same permuted key order
#pragma unroll
      for (int dt = 0; dt < 4; ++dt) {
        const unsigned short* vp = vrow + (size_t)dt * 16 * Nc + k0 + p * 32 + ql * 4;
        union { short8 s; uint4 u; } vf;
        uint2 va = *(const uint2*)vp;
        uint2 vb2 = *(const uint2*)(vp + 16);
        vf.u.x = va.x; vf.u.y = va.y; vf.u.z = vb2.x; vf.u.w = vb2.y;
#pragma unroll
        for (int qt = 0; qt < 2; ++qt) acc[dt][qt] = mfma16(vf.s, pf[qt], acc[dt][qt]);
      }
    }
  }

  // ---- epilogue: lane(ql,l16) holds O[q = qt*16+l16 (local)][d = dt*16+ql*4+r]
#pragma unroll
  for (int qt = 0; qt < 2; ++qt) {
    float ss = 0.f;
#pragma unroll
    for (int dt = 0; dt < 4; ++dt)
#pragma unroll
      for (int r = 0; r < 4; ++r) { float v = acc[dt][qt][r]; ss += v * v; }
    ss += __shfl_xor(ss, 16, 64);
    ss += __shfl_xor(ss, 32, 64);
    float nrm = sqrtf(ss);
    float sc = tanhf(nrm) / fmaxf(nrm, 1e-12f);
    int q = qw0 + qt * 16 + l16;
    size_t gbase = ((size_t)(b * Nc + q)) * DIc + h * 80 + DKc;  // gate slice of QG
#pragma unroll
    for (int dt = 0; dt < 4; ++dt) {
      uint2 gu = *(const uint2*)&QG[gbase + dt * 16 + ql * 4];
      float o[4];
#pragma unroll
      for (int r = 0; r < 4; ++r) {
        unsigned short gb = (r < 2) ? (unsigned short)(gu.x >> (16 * r))
                                    : (unsigned short)(gu.y >> (16 * (r - 2)));
        float x = bf2f(gb);
        float s = x / (1.f + __expf(-x));
        float e2 = __expf(2.f * s);
        float g = 1.f - 2.f / (e2 + 1.f);  // tanh(s)
        o[r] = acc[dt][qt][r] * sc * g;
      }
      uint2 w;
      w.x = pack2bf(o[0], o[1]);
      w.y = pack2bf(o[2], o[3]);
      *(uint2*)&of[wave * 32 + qt * 16 + l16][dt * 16 + ql * 4] = w;
    }
  }
  __syncthreads();
  {
    int row = tid >> 1, cb = (tid & 1) * 32;
    size_t obase = ((size_t)(b * Nc + q0 + row)) * (Hc * DVc) + h * DVc + cb;
#pragma unroll
    for (int i = 0; i < 4; ++i)
      *(ushort8*)&outpre[obase + i * 8] = *(const ushort8*)&of[row][cb + i * 8];
  }
}

extern "C" void kernel_launch(void* const* d_in, const int* in_sizes, int n_in,
                              void* d_out, int out_size, void* d_ws, size_t ws_size,
                              hipStream_t stream) {
  const float* X = (const float*)d_in[0];     // (4,2048,1024)
  const float* Wqg = (const float*)d_in[1];   // (1024,1280)
  const float* Wkv = (const float*)d_in[2];   // (1024,1280)
  const float* Wout = (const float*)d_in[3];  // (1024,1024)
  float* out = (float*)d_out;
  (void)in_sizes; (void)n_in; (void)out_size; (void)ws_size;

  char* ws = (char*)d_ws;
  size_t off = 0;
  auto alloc = [&](size_t bytes) {
    void* p = ws + off;
    off += (bytes + 255) & ~(size_t)255;
    return p;
  };
  unsigned short* Xbf   = (unsigned short*)alloc((size_t)Mc * Dc * 2);            // 16 MB
  unsigned short* WqgT  = (unsigned short*)alloc((size_t)DIc * Dc * 2);           // 2.5 MB
  unsigned short* WkvT  = (unsigned short*)alloc((size_t)DIc * Dc * 2);
  unsigned short* WoutT = (unsigned short*)alloc((size_t)Dc * Dc * 2);            // 2 MB
  unsigned short* QG    = (unsigned short*)alloc((size_t)Mc * DIc * 2);           // 20 MB
  unsigned short* KV    = (unsigned short*)alloc((size_t)Mc * DIc * 2);           // 20 MB
  unsigned short* Qn    = (unsigned short*)alloc((size_t)Bc * Hc * Nc * DKc * 2); // 4 MB
  unsigned short* Kn    = (unsigned short*)alloc((size_t)Bc * Hc * Nc * DKc * 2); // 4 MB
  unsigned short* Vtg   = (unsigned short*)alloc((size_t)Bc * Hc * Nc * DVc * 2); // 16 MB
  unsigned short* outpre = Xbf;  // Xbf dead after projection GEMMs; same size

  convert_x<<<(Mc * Dc / 8) / 256, 256, 0, stream>>>(X, Xbf, Mc * Dc / 8);
  transpose_convert<<<dim3(Dc / 64, DIc / 64), 256, 0, stream>>>(Wqg, WqgT, Dc, DIc);
  transpose_convert<<<dim3(Dc / 64, DIc / 64), 256, 0, stream>>>(Wkv, WkvT, Dc, DIc);
  transpose_convert<<<dim3(Dc / 64, Dc / 64), 256, 0, stream>>>(Wout, WoutT, Dc, Dc);
  gemm_glds<1><<<dim3(Mc / 128, DIc / 128), 256, 0, stream>>>(Xbf, WqgT, QG, Mc, DIc, Dc);
  gemm_glds<1><<<dim3(Mc / 128, DIc / 128), 256, 0, stream>>>(Xbf, WkvT, KV, Mc, DIc, Dc);
  norm_kernel<<<(Mc * Hc) / 256, 256, 0, stream>>>(QG, KV, Qn, Kn, Vtg);
  attn_kernel<<<1024, 256, 0, stream>>>(Qn, Kn, Vtg, QG, outpre);
  gemm_glds<0><<<dim3(Mc / 128, Dc / 128), 256, 0, stream>>>(outpre, WoutT, out, Mc, Dc, Dc);
}

// Round 6
// 268.482 us; speedup vs baseline: 1.6327x; 1.6327x over previous
//
#include <hip/hip_runtime.h>
#include <cstdint>
#include <cstddef>

typedef __attribute__((ext_vector_type(8))) short short8;
typedef __attribute__((ext_vector_type(8))) unsigned short ushort8;
typedef __attribute__((ext_vector_type(4))) float f32x4;

#define DEV static __device__ __forceinline__

DEV unsigned short f2bf(float x) {
  union { float f; unsigned u; } v; v.f = x;
  unsigned r = v.u + 0x7fffu + ((v.u >> 16) & 1u);
  return (unsigned short)(r >> 16);
}
DEV float bf2f(unsigned short u) {
  union { unsigned u; float f; } v; v.u = ((unsigned)u) << 16;
  return v.f;
}
// pack two fp32 -> bf16x2 dword, round-half-up; v_perm merges the two hi16s
DEV unsigned pack2bf(float lo, float hi) {
  union { float f; unsigned u; } a, b; a.f = lo; b.f = hi;
  return __builtin_amdgcn_perm(b.u + 0x8000u, a.u + 0x8000u, 0x07060302u);
}
DEV f32x4 mfma16(short8 a, short8 b, f32x4 c) {
  return __builtin_amdgcn_mfma_f32_16x16x32_bf16(a, b, c, 0, 0, 0);
}

// async global->LDS, 16B per lane; LDS dst = wave-uniform base + lane*16
typedef __attribute__((address_space(1))) unsigned int g_u32;
typedef __attribute__((address_space(3))) unsigned int l_u32;
DEV void glds16(const unsigned short* g, unsigned short* l) {
  __builtin_amdgcn_global_load_lds((g_u32*)g, (l_u32*)l, 16, 0, 0);
}

constexpr int Bc = 4, Nc = 2048, Dc = 1024, Hc = 16, DKc = 16, DVc = 64, DIc = 1280;
constexpr int Mc = Bc * Nc;  // 8192

// ---------------- elementwise fp32 -> bf16 ----------------
__global__ __launch_bounds__(256) void convert_x(const float* __restrict__ X,
                                                 unsigned short* __restrict__ Xb, int total8) {
  int i = blockIdx.x * 256 + threadIdx.x;
  if (i >= total8) return;
  const float4* p = (const float4*)(X + (size_t)i * 8);
  float4 a = p[0], b = p[1];
  ushort8 o;
  o[0] = f2bf(a.x); o[1] = f2bf(a.y); o[2] = f2bf(a.z); o[3] = f2bf(a.w);
  o[4] = f2bf(b.x); o[5] = f2bf(b.y); o[6] = f2bf(b.z); o[7] = f2bf(b.w);
  *(ushort8*)(Xb + (size_t)i * 8) = o;
}

// ---------------- W[K][N] fp32 -> WT[N][K] bf16 ----------------
__global__ __launch_bounds__(256) void transpose_convert(const float* __restrict__ W,
                                                         unsigned short* __restrict__ WT,
                                                         int K, int N) {
  __shared__ unsigned short t[64][72];
  int k0 = blockIdx.x * 64, n0 = blockIdx.y * 64;
  int tid = threadIdx.x;
#pragma unroll
  for (int it = 0; it < 16; ++it) {
    int f = it * 256 + tid;
    int r = f >> 6, c = f & 63;
    t[c][r] = f2bf(W[(size_t)(k0 + r) * N + n0 + c]);
  }
  __syncthreads();
#pragma unroll
  for (int it = 0; it < 16; ++it) {
    int f = it * 256 + tid;
    int r = f >> 6, c = f & 63;
    WT[(size_t)(n0 + r) * K + k0 + c] = t[r][c];
  }
}

// ---------------- C[M][N] = A[M][K] * BT[N][K]^T, m97-style global_load_lds ----------------
template <int OUT_BF16>
__global__ __launch_bounds__(256) void gemm_glds(const unsigned short* __restrict__ A,
                                                 const unsigned short* __restrict__ BT,
                                                 void* __restrict__ Cout,
                                                 int Mq, int Nq, int Kq) {
  __shared__ unsigned short As[128 * 64];
  __shared__ unsigned short Bs[128 * 64];
  int row0 = blockIdx.x * 128, col0 = blockIdx.y * 128;
  int tid = threadIdx.x, lane = tid & 63, wave = tid >> 6;
  int wm = wave >> 1, wn = wave & 1;
  int ql = lane >> 4, l16 = lane & 15;
  int r8 = lane >> 3, cbl = (lane & 7) ^ r8;

  const unsigned short* gA = A + (size_t)(row0 + wave * 32 + r8) * Kq + cbl * 8;
  const unsigned short* gB = BT + (size_t)(col0 + wave * 32 + r8) * Kq + cbl * 8;

  f32x4 acc[4][4];
#pragma unroll
  for (int i = 0; i < 4; i++)
#pragma unroll
    for (int j = 0; j < 4; j++) acc[i][j] = (f32x4){0.f, 0.f, 0.f, 0.f};

  for (int k0 = 0; k0 < Kq; k0 += 64) {
    __syncthreads();
#pragma unroll
    for (int i = 0; i < 4; ++i) {
      glds16(gA + (size_t)(i * 8) * Kq + k0, &As[(wave * 32 + i * 8) * 64]);
      glds16(gB + (size_t)(i * 8) * Kq + k0, &Bs[(wave * 32 + i * 8) * 64]);
    }
    __syncthreads();
#pragma unroll
    for (int kk = 0; kk < 64; kk += 32) {
      short8 af[4], bfr[4];
#pragma unroll
      for (int t = 0; t < 4; t++) {
        int row = wm * 64 + t * 16 + l16;
        int cb = (kk >> 3) + ql;
        af[t] = *(const short8*)&As[row * 64 + ((cb ^ (row & 7)) << 3)];
      }
#pragma unroll
      for (int t = 0; t < 4; t++) {
        int row = wn * 64 + t * 16 + l16;
        int cb = (kk >> 3) + ql;
        bfr[t] = *(const short8*)&Bs[row * 64 + ((cb ^ (row & 7)) << 3)];
      }
#pragma unroll
      for (int i = 0; i < 4; i++)
#pragma unroll
        for (int j = 0; j < 4; j++) acc[i][j] = mfma16(af[i], bfr[j], acc[i][j]);
    }
  }
#pragma unroll
  for (int i = 0; i < 4; i++)
#pragma unroll
    for (int j = 0; j < 4; j++)
#pragma unroll
      for (int r = 0; r < 4; r++) {
        int rr = row0 + wm * 64 + i * 16 + ql * 4 + r;
        int cc = col0 + wn * 64 + j * 16 + l16;
        if (OUT_BF16)
          ((unsigned short*)Cout)[(size_t)rr * Nq + cc] = f2bf(acc[i][j][r]);
        else
          ((float*)Cout)[(size_t)rr * Nq + cc] = acc[i][j][r];
      }
}

// ---------------- per-head normalize (gates handled in attn epilogue) ----------------
__global__ __launch_bounds__(256) void norm_kernel(const unsigned short* __restrict__ QG,
                                                   const unsigned short* __restrict__ KV,
                                                   unsigned short* __restrict__ Qn,
                                                   unsigned short* __restrict__ Kn,
                                                   unsigned short* __restrict__ Vtg) {
  int g = blockIdx.x * 256 + threadIdx.x;
  int n = g & (Nc - 1), bh = g >> 11;
  int h = bh & 15, b = bh >> 4;
  size_t src = ((size_t)(b * Nc + n)) * DIc + h * 80;

  {
    ushort8 u0 = *(const ushort8*)&QG[src];
    ushort8 u1 = *(const ushort8*)&QG[src + 8];
    float q[16], ss = 0.f;
#pragma unroll
    for (int i = 0; i < 8; i++) { q[i] = bf2f(u0[i]); q[8 + i] = bf2f(u1[i]); }
#pragma unroll
    for (int i = 0; i < 16; i++) ss += q[i] * q[i];
    float sc = 1.f / fmaxf(sqrtf(ss), 1e-12f);
    ushort8 o0, o1;
#pragma unroll
    for (int i = 0; i < 8; i++) { o0[i] = f2bf(q[i] * sc); o1[i] = f2bf(q[8 + i] * sc); }
    size_t dst = ((size_t)bh * Nc + n) * DKc;
    *(ushort8*)&Qn[dst] = o0;
    *(ushort8*)&Qn[dst + 8] = o1;
  }
  {
    ushort8 u0 = *(const ushort8*)&KV[src];
    ushort8 u1 = *(const ushort8*)&KV[src + 8];
    float q[16], ss = 0.f;
#pragma unroll
    for (int i = 0; i < 8; i++) { q[i] = bf2f(u0[i]); q[8 + i] = bf2f(u1[i]); }
#pragma unroll
    for (int i = 0; i < 16; i++) ss += q[i] * q[i];
    float sc = 1.f / fmaxf(sqrtf(ss), 1e-12f);
    ushort8 o0, o1;
#pragma unroll
    for (int i = 0; i < 8; i++) { o0[i] = f2bf(q[i] * sc); o1[i] = f2bf(q[8 + i] * sc); }
    size_t dst = ((size_t)bh * Nc + n) * DKc;
    *(ushort8*)&Kn[dst] = o0;
    *(ushort8*)&Kn[dst + 8] = o1;
  }
  {
    ushort8 u[8];
#pragma unroll
    for (int i = 0; i < 8; i++) u[i] = *(const ushort8*)&KV[src + 16 + i * 8];
    float ss = 0.f;
#pragma unroll
    for (int i = 0; i < 8; i++)
#pragma unroll
      for (int j = 0; j < 8; j++) { float x = bf2f(u[i][j]); ss += x * x; }
    float sc = 1.f / fmaxf(sqrtf(ss), 1e-12f);
#pragma unroll
    for (int i = 0; i < 8; i++)
#pragma unroll
      for (int j = 0; j < 8; j++) {
        int d = i * 8 + j;
        Vtg[((size_t)bh * DVc + d) * Nc + n] = f2bf(bf2f(u[i][j]) * sc);
      }
  }
}

// ---------------- relu^2 attention: register P-feed + V^T in LDS (dbuf glds) ----------------
// R5 diagnosis: per-lane V global loads (16 cache lines/inst) on the dependency
// chain = latency death. Fix: V^T tiles live in LDS, staged async with
// global_load_lds, double-buffered, ONE barrier/tile. P still feeds PV directly
// from S^T C-regs (permuted-key bijection, verified R5). V tile is unpadded
// (glds constraint) with 16B-granule XOR swizzle (block m of row d -> m^(d&7));
// fragment b64 reads land at the b64 structural bank minimum.
__global__ __launch_bounds__(256, 4) void attn_kernel(const unsigned short* __restrict__ Qn,
                                                      const unsigned short* __restrict__ Kn,
                                                      const unsigned short* __restrict__ Vtg,
                                                      const unsigned short* __restrict__ QG,
                                                      unsigned short* __restrict__ outpre) {
  __shared__ unsigned short shm[2 * 64 * 128];  // vt[2][64][128] (32KB); epilogue aliases of[128][68]

  int gid = blockIdx.x;
  int xcd = gid & 7, slot = gid >> 3;
  int bh = xcd * 8 + (slot & 7);
  int q0 = (slot >> 3) * 128;
  int b = bh >> 4, h = bh & 15;
  int tid = threadIdx.x, lane = tid & 63, wave = tid >> 6;
  int ql = lane >> 4, l16 = lane & 15;
  int qw0 = q0 + wave * 32;

  const short8 zz = {0, 0, 0, 0, 0, 0, 0, 0};

  // Q fragments (B-operand of S-mfma), resident: q = qw0 + qt*16 + l16
  short8 qf[2];
#pragma unroll
  for (int qt = 0; qt < 2; ++qt)
    qf[qt] = (ql < 2)
                 ? *(const short8*)&Qn[((size_t)bh * Nc + qw0 + qt * 16 + l16) * DKc + ql * 8]
                 : zz;

  const unsigned short* krow = Kn + ((size_t)bh * Nc) * DKc;
  const unsigned short* vbase = Vtg + ((size_t)bh * DVc) * Nc;

  // V staging geometry: wave stages rows {i*16 + wave*4 + (lane>>4)}, 16B block
  // m=lane&15 fetched from global block m^(d&7) so XOR-swizzled slot is correct.
  int lr = lane >> 4, m16 = lane & 15;

  f32x4 acc[4][2];
#pragma unroll
  for (int dt = 0; dt < 4; dt++) { acc[dt][0] = (f32x4){0.f,0.f,0.f,0.f}; acc[dt][1] = (f32x4){0.f,0.f,0.f,0.f}; }

  // prologue: stage tile 0 into buf 0
#pragma unroll
  for (int i = 0; i < 4; ++i) {
    int r0 = i * 16 + wave * 4;
    int d = r0 + lr;
    glds16(vbase + (size_t)d * Nc + 0 + ((m16 ^ (d & 7)) << 3), &shm[r0 * 128]);
  }

  for (int kt = 0; kt < Nc / 128; ++kt) {
    int k0 = kt * 128;
    unsigned short* vtb = &shm[(kt & 1) * 8192];
    __syncthreads();  // drains glds for this tile; all waves done reading prev buf

    // K fragments for this tile (coalesced 512B contiguous region per frag)
    short8 kf[8];
#pragma unroll
    for (int kh = 0; kh < 8; ++kh)
      kf[kh] = (ql < 2)
                   ? *(const short8*)&krow[(size_t)(k0 + kh * 16 + l16) * DKc + ql * 8]
                   : zz;

    // async-stage next tile into the other buffer (after kf so kf waits keep it in flight)
    if (kt < Nc / 128 - 1) {
      unsigned short* nb = &shm[((kt + 1) & 1) * 8192];
      int kn0 = k0 + 128;
#pragma unroll
      for (int i = 0; i < 4; ++i) {
        int r0 = i * 16 + wave * 4;
        int d = r0 + lr;
        glds16(vbase + (size_t)d * Nc + kn0 + ((m16 ^ (d & 7)) << 3), &nb[r0 * 128]);
      }
    }

#pragma unroll
    for (int p = 0; p < 4; ++p) {  // 32-key group [k0+p*32, +32)
      f32x4 c0[2], c1[2];
#pragma unroll
      for (int qt = 0; qt < 2; ++qt) {
        c0[qt] = mfma16(kf[2 * p], qf[qt], (f32x4){0.f, 0.f, 0.f, 0.f});
        c1[qt] = mfma16(kf[2 * p + 1], qf[qt], (f32x4){0.f, 0.f, 0.f, 0.f});
      }
      short8 pf[2];
#pragma unroll
      for (int qt = 0; qt < 2; ++qt) {
        float a0 = fmaxf(c0[qt][0], 0.f); a0 *= a0;
        float a1 = fmaxf(c0[qt][1], 0.f); a1 *= a1;
        float a2 = fmaxf(c0[qt][2], 0.f); a2 *= a2;
        float a3 = fmaxf(c0[qt][3], 0.f); a3 *= a3;
        float b0 = fmaxf(c1[qt][0], 0.f); b0 *= b0;
        float b1 = fmaxf(c1[qt][1], 0.f); b1 *= b1;
        float b2 = fmaxf(c1[qt][2], 0.f); b2 *= b2;
        float b3 = fmaxf(c1[qt][3], 0.f); b3 *= b3;
        union { short8 s; uint4 u; } w;
        w.u.x = pack2bf(a0, a1);
        w.u.y = pack2bf(a2, a3);
        w.u.z = pack2bf(b0, b1);
        w.u.w = pack2bf(b2, b3);
        pf[qt] = w.s;
      }
      // PV: A = V^T frags from LDS (XOR-swizzled granules, permuted key order)
      int tsw = (l16 & 7) << 1;
      int s1 = ((p * 8 + ql) ^ tsw) << 2;       // granule -> element offset
      int s2 = ((p * 8 + 4 + ql) ^ tsw) << 2;
#pragma unroll
      for (int dt = 0; dt < 4; ++dt) {
        const unsigned short* vrow = vtb + (dt * 16 + l16) * 128;
        union { short8 s; uint4 u; } vf;
        uint2 va = *(const uint2*)&vrow[s1];
        uint2 vb2 = *(const uint2*)&vrow[s2];
        vf.u.x = va.x; vf.u.y = va.y; vf.u.z = vb2.x; vf.u.w = vb2.y;
#pragma unroll
        for (int qt = 0; qt < 2; ++qt) acc[dt][qt] = mfma16(vf.s, pf[qt], acc[dt][qt]);
      }
    }
  }

  __syncthreads();  // all waves done with vt before 'of' aliases shm
  unsigned short(*of)[68] = (unsigned short(*)[68])shm;

  // epilogue: lane(ql,l16) holds O[q = qt*16+l16 (local)][d = dt*16+ql*4+r]
#pragma unroll
  for (int qt = 0; qt < 2; ++qt) {
    float ss = 0.f;
#pragma unroll
    for (int dt = 0; dt < 4; ++dt)
#pragma unroll
      for (int r = 0; r < 4; ++r) { float v = acc[dt][qt][r]; ss += v * v; }
    ss += __shfl_xor(ss, 16, 64);
    ss += __shfl_xor(ss, 32, 64);
    float nrm = sqrtf(ss);
    float sc = tanhf(nrm) / fmaxf(nrm, 1e-12f);
    int q = qw0 + qt * 16 + l16;
    size_t gbase = ((size_t)(b * Nc + q)) * DIc + h * 80 + DKc;  // gate slice of QG
#pragma unroll
    for (int dt = 0; dt < 4; ++dt) {
      uint2 gu = *(const uint2*)&QG[gbase + dt * 16 + ql * 4];
      float o[4];
#pragma unroll
      for (int r = 0; r < 4; ++r) {
        unsigned short gb = (r < 2) ? (unsigned short)(gu.x >> (16 * r))
                                    : (unsigned short)(gu.y >> (16 * (r - 2)));
        float x = bf2f(gb);
        float s = x / (1.f + __expf(-x));
        float e2 = __expf(2.f * s);
        float g = 1.f - 2.f / (e2 + 1.f);  // tanh(s)
        o[r] = acc[dt][qt][r] * sc * g;
      }
      uint2 w;
      w.x = pack2bf(o[0], o[1]);
      w.y = pack2bf(o[2], o[3]);
      *(uint2*)&of[wave * 32 + qt * 16 + l16][dt * 16 + ql * 4] = w;
    }
  }
  __syncthreads();
  {
    int row = tid >> 1, cb = (tid & 1) * 32;
    size_t obase = ((size_t)(b * Nc + q0 + row)) * (Hc * DVc) + h * DVc + cb;
#pragma unroll
    for (int i = 0; i < 4; ++i)
      *(ushort8*)&outpre[obase + i * 8] = *(const ushort8*)&of[row][cb + i * 8];
  }
}

extern "C" void kernel_launch(void* const* d_in, const int* in_sizes, int n_in,
                              void* d_out, int out_size, void* d_ws, size_t ws_size,
                              hipStream_t stream) {
  const float* X = (const float*)d_in[0];     // (4,2048,1024)
  const float* Wqg = (const float*)d_in[1];   // (1024,1280)
  const float* Wkv = (const float*)d_in[2];   // (1024,1280)
  const float* Wout = (const float*)d_in[3];  // (1024,1024)
  float* out = (float*)d_out;
  (void)in_sizes; (void)n_in; (void)out_size; (void)ws_size;

  char* ws = (char*)d_ws;
  size_t off = 0;
  auto alloc = [&](size_t bytes) {
    void* p = ws + off;
    off += (bytes + 255) & ~(size_t)255;
    return p;
  };
  unsigned short* Xbf   = (unsigned short*)alloc((size_t)Mc * Dc * 2);            // 16 MB
  unsigned short* WqgT  = (unsigned short*)alloc((size_t)DIc * Dc * 2);           // 2.5 MB
  unsigned short* WkvT  = (unsigned short*)alloc((size_t)DIc * Dc * 2);
  unsigned short* WoutT = (unsigned short*)alloc((size_t)Dc * Dc * 2);            // 2 MB
  unsigned short* QG    = (unsigned short*)alloc((size_t)Mc * DIc * 2);           // 20 MB
  unsigned short* KV    = (unsigned short*)alloc((size_t)Mc * DIc * 2);           // 20 MB
  unsigned short* Qn    = (unsigned short*)alloc((size_t)Bc * Hc * Nc * DKc * 2); // 4 MB
  unsigned short* Kn    = (unsigned short*)alloc((size_t)Bc * Hc * Nc * DKc * 2); // 4 MB
  unsigned short* Vtg   = (unsigned short*)alloc((size_t)Bc * Hc * Nc * DVc * 2); // 16 MB
  unsigned short* outpre = Xbf;  // Xbf dead after projection GEMMs; same size

  convert_x<<<(Mc * Dc / 8) / 256, 256, 0, stream>>>(X, Xbf, Mc * Dc / 8);
  transpose_convert<<<dim3(Dc / 64, DIc / 64), 256, 0, stream>>>(Wqg, WqgT, Dc, DIc);
  transpose_convert<<<dim3(Dc / 64, DIc / 64), 256, 0, stream>>>(Wkv, WkvT, Dc, DIc);
  transpose_convert<<<dim3(Dc / 64, Dc / 64), 256, 0, stream>>>(Wout, WoutT, Dc, Dc);
  gemm_glds<1><<<dim3(Mc / 128, DIc / 128), 256, 0, stream>>>(Xbf, WqgT, QG, Mc, DIc, Dc);
  gemm_glds<1><<<dim3(Mc / 128, DIc / 128), 256, 0, stream>>>(Xbf, WkvT, KV, Mc, DIc, Dc);
  norm_kernel<<<(Mc * Hc) / 256, 256, 0, stream>>>(QG, KV, Qn, Kn, Vtg);
  attn_kernel<<<1024, 256, 0, stream>>>(Qn, Kn, Vtg, QG, outpre);
  gemm_glds<0><<<dim3(Mc / 128, Dc / 128), 256, 0, stream>>>(outpre, WoutT, out, Mc, Dc, Dc);
}

// Round 8
// 256.667 us; speedup vs baseline: 1.7079x; 1.0460x over previous
//
#include <hip/hip_runtime.h>
#include <cstdint>
#include <cstddef>

typedef __attribute__((ext_vector_type(8))) short short8;
typedef __attribute__((ext_vector_type(8))) unsigned short ushort8;
typedef __attribute__((ext_vector_type(4))) float f32x4;
typedef __attribute__((ext_vector_type(8))) _Float16 half8;
typedef __attribute__((ext_vector_type(2))) __fp16 fp16x2;

#define DEV static __device__ __forceinline__

DEV unsigned short f2bf(float x) {
  union { float f; unsigned u; } v; v.f = x;
  unsigned r = v.u + 0x7fffu + ((v.u >> 16) & 1u);
  return (unsigned short)(r >> 16);
}
DEV float bf2f(unsigned short u) {
  union { unsigned u; float f; } v; v.u = ((unsigned)u) << 16;
  return v.f;
}
DEV unsigned pack2bf(float lo, float hi) {
  union { float f; unsigned u; } a, b; a.f = lo; b.f = hi;
  return __builtin_amdgcn_perm(b.u + 0x8000u, a.u + 0x8000u, 0x07060302u);
}
DEV f32x4 mfma16(short8 a, short8 b, f32x4 c) {
  return __builtin_amdgcn_mfma_f32_16x16x32_bf16(a, b, c, 0, 0, 0);
}
DEV f32x4 mfma16h(half8 a, half8 b, f32x4 c) {
  return __builtin_amdgcn_mfma_f32_16x16x32_f16(a, b, c, 0, 0, 0);
}

// async global->LDS, 16B per lane; LDS dst = wave-uniform base + lane*16
typedef __attribute__((address_space(1))) unsigned int g_u32;
typedef __attribute__((address_space(3))) unsigned int l_u32;
DEV void glds16(const unsigned short* g, unsigned short* l) {
  __builtin_amdgcn_global_load_lds((g_u32*)g, (l_u32*)l, 16, 0, 0);
}

constexpr int Bc = 4, Nc = 2048, Dc = 1024, Hc = 16, DKc = 16, DVc = 64, DIc = 1280;
constexpr int Mc = Bc * Nc;  // 8192

// ---------------- elementwise fp32 -> bf16 ----------------
__global__ __launch_bounds__(256) void convert_x(const float* __restrict__ X,
                                                 unsigned short* __restrict__ Xb, int total8) {
  int i = blockIdx.x * 256 + threadIdx.x;
  if (i >= total8) return;
  const float4* p = (const float4*)(X + (size_t)i * 8);
  float4 a = p[0], b = p[1];
  ushort8 o;
  o[0] = f2bf(a.x); o[1] = f2bf(a.y); o[2] = f2bf(a.z); o[3] = f2bf(a.w);
  o[4] = f2bf(b.x); o[5] = f2bf(b.y); o[6] = f2bf(b.z); o[7] = f2bf(b.w);
  *(ushort8*)(Xb + (size_t)i * 8) = o;
}

// ---------------- W[K][N] fp32 -> WT[N][K] bf16 ----------------
__global__ __launch_bounds__(256) void transpose_convert(const float* __restrict__ W,
                                                         unsigned short* __restrict__ WT,
                                                         int K, int N) {
  __shared__ unsigned short t[64][72];
  int k0 = blockIdx.x * 64, n0 = blockIdx.y * 64;
  int tid = threadIdx.x;
#pragma unroll
  for (int it = 0; it < 16; ++it) {
    int f = it * 256 + tid;
    int r = f >> 6, c = f & 63;
    t[c][r] = f2bf(W[(size_t)(k0 + r) * N + n0 + c]);
  }
  __syncthreads();
#pragma unroll
  for (int it = 0; it < 16; ++it) {
    int f = it * 256 + tid;
    int r = f >> 6, c = f & 63;
    WT[(size_t)(n0 + r) * K + k0 + c] = t[r][c];
  }
}

// ---------------- fused projection GEMM: C = Xbf * [WqgT | WkvT]^T ----------------
// BT rows [0,1280) = WqgT, [1280,2560) = WkvT (contiguous). 128-col tiles never
// straddle the 1280 boundary (1280 % 128 == 0) -> per-block output select.
__global__ __launch_bounds__(256) void gemm_proj(const unsigned short* __restrict__ A,
                                                 const unsigned short* __restrict__ BT,
                                                 unsigned short* __restrict__ QG,
                                                 unsigned short* __restrict__ KV,
                                                 int Kq) {
  __shared__ unsigned short As[128 * 64];
  __shared__ unsigned short Bs[128 * 64];
  int row0 = blockIdx.x * 128, col0 = blockIdx.y * 128;
  int tid = threadIdx.x, lane = tid & 63, wave = tid >> 6;
  int wm = wave >> 1, wn = wave & 1;
  int ql = lane >> 4, l16 = lane & 15;
  int r8 = lane >> 3, cbl = (lane & 7) ^ r8;

  unsigned short* dst = (col0 >= DIc) ? KV : QG;
  int c0l = (col0 >= DIc) ? col0 - DIc : col0;

  const unsigned short* gA = A + (size_t)(row0 + wave * 32 + r8) * Kq + cbl * 8;
  const unsigned short* gB = BT + (size_t)(col0 + wave * 32 + r8) * Kq + cbl * 8;

  f32x4 acc[4][4];
#pragma unroll
  for (int i = 0; i < 4; i++)
#pragma unroll
    for (int j = 0; j < 4; j++) acc[i][j] = (f32x4){0.f, 0.f, 0.f, 0.f};

  for (int k0 = 0; k0 < Kq; k0 += 64) {
    __syncthreads();
#pragma unroll
    for (int i = 0; i < 4; ++i) {
      glds16(gA + (size_t)(i * 8) * Kq + k0, &As[(wave * 32 + i * 8) * 64]);
      glds16(gB + (size_t)(i * 8) * Kq + k0, &Bs[(wave * 32 + i * 8) * 64]);
    }
    __syncthreads();
#pragma unroll
    for (int kk = 0; kk < 64; kk += 32) {
      short8 af[4], bfr[4];
#pragma unroll
      for (int t = 0; t < 4; t++) {
        int row = wm * 64 + t * 16 + l16;
        int cb = (kk >> 3) + ql;
        af[t] = *(const short8*)&As[row * 64 + ((cb ^ (row & 7)) << 3)];
      }
#pragma unroll
      for (int t = 0; t < 4; t++) {
        int row = wn * 64 + t * 16 + l16;
        int cb = (kk >> 3) + ql;
        bfr[t] = *(const short8*)&Bs[row * 64 + ((cb ^ (row & 7)) << 3)];
      }
#pragma unroll
      for (int i = 0; i < 4; i++)
#pragma unroll
        for (int j = 0; j < 4; j++) acc[i][j] = mfma16(af[i], bfr[j], acc[i][j]);
    }
  }
#pragma unroll
  for (int i = 0; i < 4; i++)
#pragma unroll
    for (int j = 0; j < 4; j++)
#pragma unroll
      for (int r = 0; r < 4; r++) {
        int rr = row0 + wm * 64 + i * 16 + ql * 4 + r;
        int cc = c0l + wn * 64 + j * 16 + l16;
        dst[(size_t)rr * DIc + cc] = f2bf(acc[i][j][r]);
      }
}

// ---------------- C[M][N] = A[M][K] * BT[N][K]^T (final GEMM, fp32 out) ----------------
__global__ __launch_bounds__(256) void gemm_glds(const unsigned short* __restrict__ A,
                                                 const unsigned short* __restrict__ BT,
                                                 float* __restrict__ Cout,
                                                 int Mq, int Nq, int Kq) {
  __shared__ unsigned short As[128 * 64];
  __shared__ unsigned short Bs[128 * 64];
  int row0 = blockIdx.x * 128, col0 = blockIdx.y * 128;
  int tid = threadIdx.x, lane = tid & 63, wave = tid >> 6;
  int wm = wave >> 1, wn = wave & 1;
  int ql = lane >> 4, l16 = lane & 15;
  int r8 = lane >> 3, cbl = (lane & 7) ^ r8;

  const unsigned short* gA = A + (size_t)(row0 + wave * 32 + r8) * Kq + cbl * 8;
  const unsigned short* gB = BT + (size_t)(col0 + wave * 32 + r8) * Kq + cbl * 8;

  f32x4 acc[4][4];
#pragma unroll
  for (int i = 0; i < 4; i++)
#pragma unroll
    for (int j = 0; j < 4; j++) acc[i][j] = (f32x4){0.f, 0.f, 0.f, 0.f};

  for (int k0 = 0; k0 < Kq; k0 += 64) {
    __syncthreads();
#pragma unroll
    for (int i = 0; i < 4; ++i) {
      glds16(gA + (size_t)(i * 8) * Kq + k0, &As[(wave * 32 + i * 8) * 64]);
      glds16(gB + (size_t)(i * 8) * Kq + k0, &Bs[(wave * 32 + i * 8) * 64]);
    }
    __syncthreads();
#pragma unroll
    for (int kk = 0; kk < 64; kk += 32) {
      short8 af[4], bfr[4];
#pragma unroll
      for (int t = 0; t < 4; t++) {
        int row = wm * 64 + t * 16 + l16;
        int cb = (kk >> 3) + ql;
        af[t] = *(const short8*)&As[row * 64 + ((cb ^ (row & 7)) << 3)];
      }
#pragma unroll
      for (int t = 0; t < 4; t++) {
        int row = wn * 64 + t * 16 + l16;
        int cb = (kk >> 3) + ql;
        bfr[t] = *(const short8*)&Bs[row * 64 + ((cb ^ (row & 7)) << 3)];
      }
#pragma unroll
      for (int i = 0; i < 4; i++)
#pragma unroll
        for (int j = 0; j < 4; j++) acc[i][j] = mfma16(af[i], bfr[j], acc[i][j]);
    }
  }
#pragma unroll
  for (int i = 0; i < 4; i++)
#pragma unroll
    for (int j = 0; j < 4; j++)
#pragma unroll
      for (int r = 0; r < 4; r++) {
        int rr = row0 + wm * 64 + i * 16 + ql * 4 + r;
        int cc = col0 + wn * 64 + j * 16 + l16;
        Cout[(size_t)rr * Nq + cc] = acc[i][j][r];
      }
}

// ---------------- per-head normalize -> fp16 (Q/K zero-padded to 32 dims) ----------------
__global__ __launch_bounds__(256) void norm_kernel(const unsigned short* __restrict__ QG,
                                                   const unsigned short* __restrict__ KV,
                                                   unsigned short* __restrict__ Qn,   // fp16 [bh][n][32]
                                                   unsigned short* __restrict__ Kn,   // fp16 [bh][n][32]
                                                   unsigned short* __restrict__ Vtg)  // fp16 [bh][d][n]
{
  int g = blockIdx.x * 256 + threadIdx.x;
  int n = g & (Nc - 1), bh = g >> 11;
  int h = bh & 15, b = bh >> 4;
  size_t src = ((size_t)(b * Nc + n)) * DIc + h * 80;
  const ushort8 zeros = {0, 0, 0, 0, 0, 0, 0, 0};

  {
    ushort8 u0 = *(const ushort8*)&QG[src];
    ushort8 u1 = *(const ushort8*)&QG[src + 8];
    float q[16], ss = 0.f;
#pragma unroll
    for (int i = 0; i < 8; i++) { q[i] = bf2f(u0[i]); q[8 + i] = bf2f(u1[i]); }
#pragma unroll
    for (int i = 0; i < 16; i++) ss += q[i] * q[i];
    float sc = 1.f / fmaxf(sqrtf(ss), 1e-12f);
    half8 o0, o1;
#pragma unroll
    for (int i = 0; i < 8; i++) { o0[i] = (_Float16)(q[i] * sc); o1[i] = (_Float16)(q[8 + i] * sc); }
    size_t dst = ((size_t)bh * Nc + n) * 32;
    *(half8*)&Qn[dst] = o0;
    *(half8*)&Qn[dst + 8] = o1;
    *(ushort8*)&Qn[dst + 16] = zeros;
    *(ushort8*)&Qn[dst + 24] = zeros;
  }
  {
    ushort8 u0 = *(const ushort8*)&KV[src];
    ushort8 u1 = *(const ushort8*)&KV[src + 8];
    float q[16], ss = 0.f;
#pragma unroll
    for (int i = 0; i < 8; i++) { q[i] = bf2f(u0[i]); q[8 + i] = bf2f(u1[i]); }
#pragma unroll
    for (int i = 0; i < 16; i++) ss += q[i] * q[i];
    float sc = 1.f / fmaxf(sqrtf(ss), 1e-12f);
    half8 o0, o1;
#pragma unroll
    for (int i = 0; i < 8; i++) { o0[i] = (_Float16)(q[i] * sc); o1[i] = (_Float16)(q[8 + i] * sc); }
    size_t dst = ((size_t)bh * Nc + n) * 32;
    *(half8*)&Kn[dst] = o0;
    *(half8*)&Kn[dst + 8] = o1;
    *(ushort8*)&Kn[dst + 16] = zeros;
    *(ushort8*)&Kn[dst + 24] = zeros;
  }
  {
    ushort8 u[8];
#pragma unroll
    for (int i = 0; i < 8; i++) u[i] = *(const ushort8*)&KV[src + 16 + i * 8];
    float ss = 0.f;
#pragma unroll
    for (int i = 0; i < 8; i++)
#pragma unroll
      for (int j = 0; j < 8; j++) { float x = bf2f(u[i][j]); ss += x * x; }
    float sc = 1.f / fmaxf(sqrtf(ss), 1e-12f);
#pragma unroll
    for (int i = 0; i < 8; i++)
#pragma unroll
      for (int j = 0; j < 8; j++) {
        int d = i * 8 + j;
        union { _Float16 h; unsigned short us; } cv;
        cv.h = (_Float16)(bf2f(u[i][j]) * sc);
        Vtg[((size_t)bh * DVc + d) * Nc + n] = cv.us;
      }
  }
}

// ---------------- relu^2 attention, fp16 datapath ----------------
// R6 was VALU-issue-bound (71% VALUBusy): relu^2+bf16 pack = 3.5 VALU/P-value.
// fp16: v_cvt_pkrtz + v_pk_max_f16 + v_pk_mul_f16 = 1.5/value; padded Q/K kill
// the ql<2 cndmask path. Structure (dbuf glds V-tiles, register P-feed with
// permuted-key bijection, 1 barrier/tile) verified R6.
__global__ __launch_bounds__(256, 4) void attn_kernel(const unsigned short* __restrict__ Qn,
                                                      const unsigned short* __restrict__ Kn,
                                                      const unsigned short* __restrict__ Vtg,
                                                      const unsigned short* __restrict__ QG,
                                                      unsigned short* __restrict__ outpre) {
  __shared__ unsigned short shm[2 * 64 * 128];  // vt[2][64][128] (32KB); epilogue aliases of[128][68]

  int gid = blockIdx.x;
  int xcd = gid & 7, slot = gid >> 3;
  int bh = xcd * 8 + (slot & 7);
  int q0 = (slot >> 3) * 128;
  int b = bh >> 4, h = bh & 15;
  int tid = threadIdx.x, lane = tid & 63, wave = tid >> 6;
  int ql = lane >> 4, l16 = lane & 15;
  int qw0 = q0 + wave * 32;

  // Q fragments (B-operand of S-mfma), resident: q = qw0 + qt*16 + l16
  half8 qf[2];
#pragma unroll
  for (int qt = 0; qt < 2; ++qt)
    qf[qt] = *(const half8*)&Qn[((size_t)bh * Nc + qw0 + qt * 16 + l16) * 32 + ql * 8];

  const unsigned short* krow = Kn + ((size_t)bh * Nc) * 32;
  const unsigned short* vbase = Vtg + ((size_t)bh * DVc) * Nc;

  int lr = lane >> 4, m16 = lane & 15;

  f32x4 acc[4][2];
#pragma unroll
  for (int dt = 0; dt < 4; dt++) { acc[dt][0] = (f32x4){0.f,0.f,0.f,0.f}; acc[dt][1] = (f32x4){0.f,0.f,0.f,0.f}; }

  // prologue: stage V tile 0 into buf 0
#pragma unroll
  for (int i = 0; i < 4; ++i) {
    int r0 = i * 16 + wave * 4;
    int d = r0 + lr;
    glds16(vbase + (size_t)d * Nc + 0 + ((m16 ^ (d & 7)) << 3), &shm[r0 * 128]);
  }

  for (int kt = 0; kt < Nc / 128; ++kt) {
    int k0 = kt * 128;
    unsigned short* vtb = &shm[(kt & 1) * 8192];
    __syncthreads();  // drains glds for this tile; all waves done reading prev buf

    // K fragments for this tile
    half8 kf[8];
#pragma unroll
    for (int kh = 0; kh < 8; ++kh)
      kf[kh] = *(const half8*)&krow[(size_t)(k0 + kh * 16 + l16) * 32 + ql * 8];

    // async-stage next V tile into the other buffer
    if (kt < Nc / 128 - 1) {
      unsigned short* nb = &shm[((kt + 1) & 1) * 8192];
      int kn0 = k0 + 128;
#pragma unroll
      for (int i = 0; i < 4; ++i) {
        int r0 = i * 16 + wave * 4;
        int d = r0 + lr;
        glds16(vbase + (size_t)d * Nc + kn0 + ((m16 ^ (d & 7)) << 3), &nb[r0 * 128]);
      }
    }

#pragma unroll
    for (int p = 0; p < 4; ++p) {  // 32-key group [k0+p*32, +32)
      f32x4 c0[2], c1[2];
#pragma unroll
      for (int qt = 0; qt < 2; ++qt) {
        c0[qt] = mfma16h(kf[2 * p], qf[qt], (f32x4){0.f, 0.f, 0.f, 0.f});
        c1[qt] = mfma16h(kf[2 * p + 1], qf[qt], (f32x4){0.f, 0.f, 0.f, 0.f});
      }
      // relu^2 in packed fp16: pkrtz -> pk_max -> pk_mul
      half8 pf[2];
#pragma unroll
      for (int qt = 0; qt < 2; ++qt) {
        union { half8 h; fp16x2 p2[4]; } w;
        fp16x2 t0 = __builtin_amdgcn_cvt_pkrtz(c0[qt][0], c0[qt][1]);
        fp16x2 t1 = __builtin_amdgcn_cvt_pkrtz(c0[qt][2], c0[qt][3]);
        fp16x2 t2 = __builtin_amdgcn_cvt_pkrtz(c1[qt][0], c1[qt][1]);
        fp16x2 t3 = __builtin_amdgcn_cvt_pkrtz(c1[qt][2], c1[qt][3]);
        const fp16x2 hz = {(__fp16)0, (__fp16)0};
        t0 = __builtin_elementwise_max(t0, hz); w.p2[0] = t0 * t0;
        t1 = __builtin_elementwise_max(t1, hz); w.p2[1] = t1 * t1;
        t2 = __builtin_elementwise_max(t2, hz); w.p2[2] = t2 * t2;
        t3 = __builtin_elementwise_max(t3, hz); w.p2[3] = t3 * t3;
        pf[qt] = w.h;
      }
      // PV: A = V^T frags from LDS (XOR-swizzled granules, permuted key order)
      int tsw = (l16 & 7) << 1;
      int s1 = ((p * 8 + ql) ^ tsw) << 2;
      int s2 = ((p * 8 + 4 + ql) ^ tsw) << 2;
#pragma unroll
      for (int dt = 0; dt < 4; ++dt) {
        const unsigned short* vrow = vtb + (dt * 16 + l16) * 128;
        union { half8 s; uint4 u; } vf;
        uint2 va = *(const uint2*)&vrow[s1];
        uint2 vb2 = *(const uint2*)&vrow[s2];
        vf.u.x = va.x; vf.u.y = va.y; vf.u.z = vb2.x; vf.u.w = vb2.y;
#pragma unroll
        for (int qt = 0; qt < 2; ++qt) acc[dt][qt] = mfma16h(vf.s, pf[qt], acc[dt][qt]);
      }
    }
  }

  __syncthreads();  // all waves done with vt before 'of' aliases shm
  unsigned short(*of)[68] = (unsigned short(*)[68])shm;

  // epilogue: lane(ql,l16) holds O[q = qt*16+l16 (local)][d = dt*16+ql*4+r]
#pragma unroll
  for (int qt = 0; qt < 2; ++qt) {
    float ss = 0.f;
#pragma unroll
    for (int dt = 0; dt < 4; ++dt)
#pragma unroll
      for (int r = 0; r < 4; ++r) { float v = acc[dt][qt][r]; ss += v * v; }
    ss += __shfl_xor(ss, 16, 64);
    ss += __shfl_xor(ss, 32, 64);
    float nrm = sqrtf(ss);
    float sc = tanhf(nrm) / fmaxf(nrm, 1e-12f);
    int q = qw0 + qt * 16 + l16;
    size_t gbase = ((size_t)(b * Nc + q)) * DIc + h * 80 + DKc;  // gate slice of QG
#pragma unroll
    for (int dt = 0; dt < 4; ++dt) {
      uint2 gu = *(const uint2*)&QG[gbase + dt * 16 + ql * 4];
      float o[4];
#pragma unroll
      for (int r = 0; r < 4; ++r) {
        unsigned short gb = (r < 2) ? (unsigned short)(gu.x >> (16 * r))
                                    : (unsigned short)(gu.y >> (16 * (r - 2)));
        float x = bf2f(gb);
        float s = x / (1.f + __expf(-x));
        float e2 = __expf(2.f * s);
        float g = 1.f - 2.f / (e2 + 1.f);  // tanh(s)
        o[r] = acc[dt][qt][r] * sc * g;
      }
      uint2 w;
      w.x = pack2bf(o[0], o[1]);
      w.y = pack2bf(o[2], o[3]);
      *(uint2*)&of[wave * 32 + qt * 16 + l16][dt * 16 + ql * 4] = w;
    }
  }
  __syncthreads();
  {
    int row = tid >> 1, cb = (tid & 1) * 32;
    size_t obase = ((size_t)(b * Nc + q0 + row)) * (Hc * DVc) + h * DVc + cb;
#pragma unroll
    for (int i = 0; i < 4; ++i)
      *(ushort8*)&outpre[obase + i * 8] = *(const ushort8*)&of[row][cb + i * 8];
  }
}

extern "C" void kernel_launch(void* const* d_in, const int* in_sizes, int n_in,
                              void* d_out, int out_size, void* d_ws, size_t ws_size,
                              hipStream_t stream) {
  const float* X = (const float*)d_in[0];     // (4,2048,1024)
  const float* Wqg = (const float*)d_in[1];   // (1024,1280)
  const float* Wkv = (const float*)d_in[2];   // (1024,1280)
  const float* Wout = (const float*)d_in[3];  // (1024,1024)
  float* out = (float*)d_out;
  (void)in_sizes; (void)n_in; (void)out_size; (void)ws_size;

  char* ws = (char*)d_ws;
  size_t off = 0;
  auto alloc = [&](size_t bytes) {
    void* p = ws + off;
    off += (bytes + 255) & ~(size_t)255;
    return p;
  };
  unsigned short* Xbf   = (unsigned short*)alloc((size_t)Mc * Dc * 2);            // 16 MB
  unsigned short* WqgT  = (unsigned short*)alloc((size_t)DIc * Dc * 2);           // 2.5 MB (WkvT MUST follow contiguously)
  unsigned short* WkvT  = (unsigned short*)alloc((size_t)DIc * Dc * 2);
  unsigned short* WoutT = (unsigned short*)alloc((size_t)Dc * Dc * 2);            // 2 MB
  unsigned short* QG    = (unsigned short*)alloc((size_t)Mc * DIc * 2);           // 20 MB
  unsigned short* KV    = (unsigned short*)alloc((size_t)Mc * DIc * 2);           // 20 MB
  unsigned short* Qn    = (unsigned short*)alloc((size_t)Bc * Hc * Nc * 32 * 2);  // 8 MB (fp16, padded)
  unsigned short* Kn    = (unsigned short*)alloc((size_t)Bc * Hc * Nc * 32 * 2);  // 8 MB
  unsigned short* Vtg   = (unsigned short*)alloc((size_t)Bc * Hc * Nc * DVc * 2); // 16 MB (fp16)
  unsigned short* outpre = Xbf;  // Xbf dead after projection GEMM; same size

  convert_x<<<(Mc * Dc / 8) / 256, 256, 0, stream>>>(X, Xbf, Mc * Dc / 8);
  transpose_convert<<<dim3(Dc / 64, DIc / 64), 256, 0, stream>>>(Wqg, WqgT, Dc, DIc);
  transpose_convert<<<dim3(Dc / 64, DIc / 64), 256, 0, stream>>>(Wkv, WkvT, Dc, DIc);
  transpose_convert<<<dim3(Dc / 64, Dc / 64), 256, 0, stream>>>(Wout, WoutT, Dc, Dc);
  gemm_proj<<<dim3(Mc / 128, 2 * DIc / 128), 256, 0, stream>>>(Xbf, WqgT, QG, KV, Dc);
  norm_kernel<<<(Mc * Hc) / 256, 256, 0, stream>>>(QG, KV, Qn, Kn, Vtg);
  attn_kernel<<<1024, 256, 0, stream>>>(Qn, Kn, Vtg, QG, outpre);
  gemm_glds<<<dim3(Mc / 128, Dc / 128), 256, 0, stream>>>(outpre, WoutT, out, Mc, Dc, Dc);
}